// Round 6
// baseline (196.178 us; speedup 1.0000x reference)
//
#include <hip/hip_runtime.h>

#define HH 256
#define WW 256
#define PAD 4
#define HW (HH * WW)

#define TW 32      // tile width (pixels)
#define TH 16      // tile height (pixels)
#define PR 24      // patch rows = TH + 8
#define PC 40      // patch cols = TW + 8
#define PCP 41     // padded LDS col stride (bank-conflict-free: 8 start-banks tile 32)
#define NSPLIT 4   // channel splits across blocks
#define CPB 64     // channels per block
#define NG 16      // channel groups of 4 per block
#define NSLOT 4    // ceil(PR*PC / 256) staging slots per thread

__device__ __forceinline__ void fma4(float4& a, const float4& k, float w) {
    a.x = fmaf(k.x, w, a.x);
    a.y = fmaf(k.y, w, a.y);
    a.z = fmaf(k.z, w, a.z);
    a.w = fmaf(k.w, w, a.w);
}

__global__ __launch_bounds__(256, 2)
void prop_kernel(const float* __restrict__ key, const float* __restrict__ wts,
                 float* __restrict__ out) {
    // double-buffered key patch: [buf][row][col][4ch] as float4
    __shared__ float4 smem[2][PR][PCP];

    const int tid = threadIdx.x;
    const int tw  = tid & 15;   // w-pair index 0..15
    const int th  = tid >> 4;   // h index 0..15
    const int w0  = blockIdx.x * TW;
    const int h0  = blockIdx.y * TH;
    const int c0  = blockIdx.z * CPB;
    const int h   = h0 + th;
    const int w   = w0 + 2 * tw;

    // ---- per-pixel weights for the 2 owned pixels (register/AGPR resident) ----
    float wt0[81], wt1[81];
    {
        const float* wp = wts + h * WW + w;   // w even -> 8B aligned
        #pragma unroll
        for (int t = 0; t < 81; ++t) {
            float2 v = *reinterpret_cast<const float2*>(wp + t * HW);
            wt0[t] = v.x;
            wt1[t] = v.y;
        }
    }

    // ---- hoisted staging state (computed ONCE) ----
    const float* sp[NSLOT];   // global src ptr, advances 4*HW per group
    int  sdst[NSLOT];         // LDS cell index row*PCP+col
    bool sin_[NSLOT];         // in-bounds (halo zeros otherwise)
    bool sact[NSLOT];         // slot active (tail of slot 3)
    #pragma unroll
    for (int k = 0; k < NSLOT; ++k) {
        int p   = tid + k * 256;
        bool act = p < PR * PC;
        int row = p / PC;
        int col = p - row * PC;
        int gh  = h0 - PAD + row;
        int gw  = w0 - PAD + col;
        bool inb = act && (unsigned)gh < HH && (unsigned)gw < WW;
        sact[k] = act;
        sin_[k] = inb;
        sdst[k] = row * PCP + col;
        sp[k]   = key + (size_t)c0 * HW + (inb ? (gh * WW + gw) : 0);
    }

    // ---- prologue: stage channel-group 0 into buffer 0 ----
    {
        float4 v[NSLOT];
        #pragma unroll
        for (int k = 0; k < NSLOT; ++k) {
            const float* q = sp[k];
            v[k].x = q[0];
            v[k].y = q[HW];
            v[k].z = q[2 * HW];
            v[k].w = q[3 * HW];
            if (!sin_[k]) v[k] = make_float4(0.f, 0.f, 0.f, 0.f);
            sp[k] += 4 * HW;
        }
        float4* dstb = &smem[0][0][0];
        #pragma unroll
        for (int k = 0; k < NSLOT; ++k)
            if (sact[k]) dstb[sdst[k]] = v[k];
    }
    __syncthreads();

    float* op = out + (size_t)c0 * HW + h * WW + w;

    for (int g = 0; g < NG; ++g) {
        const bool pf = (g + 1 < NG);

        // 1) issue next-group staging loads into REGISTERS (latency hides under compute)
        float4 stg[NSLOT];
        if (pf) {
            #pragma unroll
            for (int k = 0; k < NSLOT; ++k) {
                const float* q = sp[k];
                stg[k].x = q[0];
                stg[k].y = q[HW];
                stg[k].z = q[2 * HW];
                stg[k].w = q[3 * HW];
                if (!sin_[k]) stg[k] = make_float4(0.f, 0.f, 0.f, 0.f);
                sp[k] += 4 * HW;
            }
        }

        // 2) compute 2 px x 4 ch from current buffer
        const float4* bp = &smem[g & 1][0][0] + th * PCP + 2 * tw;
        float4 a0 = make_float4(0.f, 0.f, 0.f, 0.f);
        float4 a1 = make_float4(0.f, 0.f, 0.f, 0.f);
        #pragma unroll
        for (int r = 0; r < 9; ++r) {
            #pragma unroll
            for (int c = 0; c < 10; ++c) {
                float4 k4 = bp[r * PCP + c];           // ds_read_b128, imm offset
                if (c < 9)  fma4(a0, k4, wt0[r * 9 + c]);
                if (c >= 1) fma4(a1, k4, wt1[r * 9 + c - 1]);
            }
        }

        // 3) store 2 px x 4 ch (fire-and-forget)
        *reinterpret_cast<float2*>(op)          = make_float2(a0.x, a1.x);
        *reinterpret_cast<float2*>(op + HW)     = make_float2(a0.y, a1.y);
        *reinterpret_cast<float2*>(op + 2 * HW) = make_float2(a0.z, a1.z);
        *reinterpret_cast<float2*>(op + 3 * HW) = make_float2(a0.w, a1.w);
        op += 4 * HW;

        // 4) write staged regs to the other buffer (vmcnt wait lands HERE, after compute)
        if (pf) {
            float4* dstb = &smem[(g + 1) & 1][0][0];
            #pragma unroll
            for (int k = 0; k < NSLOT; ++k)
                if (sact[k]) dstb[sdst[k]] = stg[k];
        }

        // 5) single barrier per group
        __syncthreads();
    }
}

extern "C" void kernel_launch(void* const* d_in, const int* in_sizes, int n_in,
                              void* d_out, int out_size, void* d_ws, size_t ws_size,
                              hipStream_t stream) {
    const float* key = (const float*)d_in[0];   // (1,256,256,256) f32
    const float* wts = (const float*)d_in[1];   // (1,81,256,256)  f32
    float* out = (float*)d_out;                 // (1,256,256,256) f32

    dim3 grid(WW / TW, HH / TH, NSPLIT);        // 8 x 16 x 4 = 512 blocks
    prop_kernel<<<grid, 256, 0, stream>>>(key, wts, out);
}